// Round 1
// baseline (6152.605 us; speedup 1.0000x reference)
//
#include <hip/hip_runtime.h>
#include <hip/hip_bf16.h>
#include <cstdint>
#include <cstddef>

// Problem dims (fixed)
#define B_   256
#define T_   512
#define F_   128
#define CU_  512
#define DU_  512
#define NG   2048   // 4*DU
#define KX   640    // F+CU

using short8 = __attribute__((ext_vector_type(8))) short;
using f32x4  = __attribute__((ext_vector_type(4))) float;

__device__ __forceinline__ unsigned short f2bf(float x) {
    union { float f; unsigned u; } v; v.f = x;
    unsigned r = v.u + 0x7fffu + ((v.u >> 16) & 1u);   // RNE
    return (unsigned short)(r >> 16);
}
__device__ __forceinline__ float bf2f(unsigned short s) {
    union { unsigned u; float f; } v; v.u = ((unsigned)s) << 16;
    return v.f;
}
__device__ __forceinline__ float sigf(float x) {
    return 1.0f / (1.0f + exp2f(-1.44269504f * x));
}
__device__ __forceinline__ float tanh_fast(float x) {
    // tanh(x) = 1 - 2/(exp(2x)+1); robust at +-inf via exp2 saturation
    return 1.0f - 2.0f / (1.0f + exp2f(2.88539008f * x));
}

// ---------------------------------------------------------------------------
// Prep: fp32 [K][N] -> bf16 [N][K] transposed cast (K-contiguous for B-frags)
// grid (N/32, K/32), block 256
__global__ __launch_bounds__(256) void k_transpose(const float* __restrict__ src,
                                                   unsigned short* __restrict__ dst,
                                                   int K, int N) {
    __shared__ float tile[32][33];
    int x = threadIdx.x & 31, y = threadIdx.x >> 5;
    int n0 = blockIdx.x * 32, k0 = blockIdx.y * 32;
    #pragma unroll
    for (int i = 0; i < 4; ++i)
        tile[y + i * 8][x] = src[(size_t)(k0 + y + i * 8) * N + n0 + x];
    __syncthreads();
    #pragma unroll
    for (int i = 0; i < 4; ++i)
        dst[(size_t)(n0 + y + i * 8) * K + k0 + x] = f2bf(tile[x][y + i * 8]);
}

// hs[0] = bf16(h0); c working buffer (== d_out cT region) = c0
__global__ __launch_bounds__(256) void k_init(const float* __restrict__ h0,
                                              const float* __restrict__ c0,
                                              unsigned short* __restrict__ hs0,
                                              float* __restrict__ cbuf) {
    int i = blockIdx.x * 256 + threadIdx.x;   // 512 blocks * 256 = 131072
    hs0[i]  = f2bf(h0[i]);
    cbuf[i] = c0[i];
}

// ---------------------------------------------------------------------------
// K1: Zx[m][n] = X[m][:] @ W[:, n] + b[n], m = t*256+b, X = [prev_chord | conductor]
// bf16 MFMA, tile 128x128, BK=32, 256 threads (4 waves, each 64x64)
__global__ __launch_bounds__(256) void k_zx(const float* __restrict__ teacher,
                                            const float* __restrict__ conductor,
                                            const float* __restrict__ bias,
                                            const unsigned short* __restrict__ Wt,
                                            unsigned short* __restrict__ Zx) {
    __shared__ unsigned short a_lds[128][40];  // +8 pad: 2-way max on frag reads (free)
    __shared__ unsigned short b_lds[128][40];
    const int tid = threadIdx.x;
    const int lane = tid & 63, w = tid >> 6;
    const int l15 = lane & 15, q = lane >> 4;
    const int n0 = blockIdx.x * 128;
    const int m0 = blockIdx.y * 128;
    const int t  = m0 >> 8;        // 128-row tile never crosses t (B=256)
    const int bb = m0 & 255;       // 0 or 128
    const int r  = tid >> 1;       // staged row 0..127
    const int ch = (tid & 1) * 16; // column half within BK=32

    const int mw = (w >> 1) * 64, nw = (w & 1) * 64;

    f32x4 acc[4][4];
    #pragma unroll
    for (int i = 0; i < 4; ++i)
        #pragma unroll
        for (int j = 0; j < 4; ++j) acc[i][j] = (f32x4){0.f, 0.f, 0.f, 0.f};

    for (int kb = 0; kb < 20; ++kb) {
        // ---- stage A (fused prev/conductor read, fp32 -> bf16) ----
        int k0 = kb * 32 + ch;     // multiple of 16; [k0,k0+16) never crosses 128
        float av[16];
        if (k0 < F_) {
            if (t == 0) {
                #pragma unroll
                for (int j = 0; j < 16; ++j) av[j] = 0.f;
            } else {
                const float* s = teacher + ((size_t)(bb + r) * T_ + (t - 1)) * F_ + k0;
                #pragma unroll
                for (int j = 0; j < 16; ++j) av[j] = s[j];
            }
        } else {
            const float* s = conductor + ((size_t)(bb + r) * T_ + t) * CU_ + (k0 - F_);
            #pragma unroll
            for (int j = 0; j < 16; ++j) av[j] = s[j];
        }
        short8 s0, s1;
        #pragma unroll
        for (int j = 0; j < 8; ++j) { s0[j] = (short)f2bf(av[j]); s1[j] = (short)f2bf(av[j + 8]); }
        *(short8*)&a_lds[r][ch]     = s0;
        *(short8*)&a_lds[r][ch + 8] = s1;
        // ---- stage B (already bf16, K-contiguous) ----
        const unsigned short* bs = Wt + (size_t)(n0 + r) * KX + kb * 32 + ch;
        *(short8*)&b_lds[r][ch]     = *(const short8*)bs;
        *(short8*)&b_lds[r][ch + 8] = *(const short8*)(bs + 8);
        __syncthreads();
        // ---- compute: 16 MFMA / wave / stage ----
        short8 af[4], bfr[4];
        #pragma unroll
        for (int mt = 0; mt < 4; ++mt)
            af[mt] = *(const short8*)&a_lds[mw + mt * 16 + l15][q * 8];
        #pragma unroll
        for (int nt = 0; nt < 4; ++nt)
            bfr[nt] = *(const short8*)&b_lds[nw + nt * 16 + l15][q * 8];
        #pragma unroll
        for (int mt = 0; mt < 4; ++mt)
            #pragma unroll
            for (int nt = 0; nt < 4; ++nt)
                acc[mt][nt] = __builtin_amdgcn_mfma_f32_16x16x32_bf16(af[mt], bfr[nt], acc[mt][nt], 0, 0, 0);
        __syncthreads();
    }
    // epilogue: +bias, bf16 store. D layout: row = q*4+rr, col = l15 (m89-verified)
    #pragma unroll
    for (int nt = 0; nt < 4; ++nt) {
        int col = n0 + nw + nt * 16 + l15;
        float bv = bias[col];
        #pragma unroll
        for (int mt = 0; mt < 4; ++mt) {
            int row = m0 + mw + mt * 16 + q * 4;
            #pragma unroll
            for (int rr = 0; rr < 4; ++rr)
                Zx[(size_t)(row + rr) * NG + col] = f2bf(acc[mt][nt][rr] + bv);
        }
    }
}

// ---------------------------------------------------------------------------
// K2 (x512): one LSTM step. z = Zx[t] + h@U; gates; c fp32 in-place (cT region);
// h bf16 -> hs[t+1]. Grid (ns=16, mt=16), 256 thr.
// Wave: kh=w&1 (K half), di=w>>1 (16-col d half). Each lane holds i,f,g,o for the
// same d (gate tiles spaced 512 cols) -> no cross-lane gate exchange.
__global__ __launch_bounds__(256) void k_step(int t,
                                              const unsigned short* __restrict__ Zx,
                                              unsigned short* __restrict__ hs,
                                              const unsigned short* __restrict__ Ut,
                                              float* __restrict__ cbuf,
                                              float* __restrict__ hT) {
    __shared__ float zred[2][4][16][16];
    const int tid = threadIdx.x;
    const int lane = tid & 63, w = tid >> 6;
    const int l15 = lane & 15, q = lane >> 4;
    const int mt = blockIdx.y, ns = blockIdx.x;
    const int m0 = mt * 16;
    const int di = w >> 1;
    const int dsub = ns * 32 + di * 16;
    const int kh = w & 1;
    const int kbase = kh * 256;

    const unsigned short* hrow = hs + (size_t)t * (B_ * DU_);

    f32x4 acc[4];
    #pragma unroll
    for (int g = 0; g < 4; ++g) acc[g] = (f32x4){0.f, 0.f, 0.f, 0.f};

    #pragma unroll
    for (int ki = 0; ki < 8; ++ki) {
        int k = kbase + ki * 32 + q * 8;
        short8 a = *(const short8*)&hrow[(size_t)(m0 + l15) * DU_ + k];
        #pragma unroll
        for (int g = 0; g < 4; ++g) {
            short8 b = *(const short8*)&Ut[(size_t)(g * DU_ + dsub + l15) * DU_ + k];
            acc[g] = __builtin_amdgcn_mfma_f32_16x16x32_bf16(a, b, acc[g], 0, 0, 0);
        }
    }
    if (kh == 1) {
        #pragma unroll
        for (int g = 0; g < 4; ++g)
            #pragma unroll
            for (int rr = 0; rr < 4; ++rr)
                zred[di][g][q * 4 + rr][l15] = acc[g][rr];
    }
    __syncthreads();
    if (kh == 0) {
        #pragma unroll
        for (int g = 0; g < 4; ++g)
            #pragma unroll
            for (int rr = 0; rr < 4; ++rr)
                acc[g][rr] += zred[di][g][q * 4 + rr][l15];
        const int d = dsub + l15;
        #pragma unroll
        for (int rr = 0; rr < 4; ++rr) {
            int m = m0 + q * 4 + rr;              // m == batch index
            size_t zrow = ((size_t)t * B_ + m) * NG;
            float zi = acc[0][rr] + bf2f(Zx[zrow + d]);
            float zf = acc[1][rr] + bf2f(Zx[zrow + DU_ + d]);
            float zg = acc[2][rr] + bf2f(Zx[zrow + 2 * DU_ + d]);
            float zo = acc[3][rr] + bf2f(Zx[zrow + 3 * DU_ + d]);
            int ci = m * DU_ + d;
            float cold = cbuf[ci];
            float cn = sigf(zf) * cold + sigf(zi) * tanh_fast(zg);
            cbuf[ci] = cn;
            float h = sigf(zo) * tanh_fast(cn);
            hs[(size_t)(t + 1) * (B_ * DU_) + ci] = f2bf(h);
            if (t == T_ - 1) hT[ci] = h;
        }
    }
}

// ---------------------------------------------------------------------------
// K3: out[b][t][f] = sigmoid(hs[t+1][b][:] @ Wo[:, f] + bo[f]); M = T*B rows
__global__ __launch_bounds__(256) void k_out(const unsigned short* __restrict__ hs,
                                             const unsigned short* __restrict__ Wot,
                                             const float* __restrict__ bo,
                                             float* __restrict__ out) {
    const int tid = threadIdx.x;
    const int lane = tid & 63, w = tid >> 6;
    const int l15 = lane & 15, q = lane >> 4;
    const int m0 = blockIdx.x * 64 + w * 16;
    const unsigned short* hbase = hs + (size_t)(B_ * DU_);  // t+1 shift

    f32x4 acc[8];
    #pragma unroll
    for (int nt = 0; nt < 8; ++nt) acc[nt] = (f32x4){0.f, 0.f, 0.f, 0.f};

    for (int ki = 0; ki < 16; ++ki) {
        int k = ki * 32 + q * 8;
        short8 a = *(const short8*)&hbase[(size_t)(m0 + l15) * DU_ + k];
        #pragma unroll
        for (int nt = 0; nt < 8; ++nt) {
            short8 b = *(const short8*)&Wot[(size_t)(nt * 16 + l15) * DU_ + k];
            acc[nt] = __builtin_amdgcn_mfma_f32_16x16x32_bf16(a, b, acc[nt], 0, 0, 0);
        }
    }
    #pragma unroll
    for (int nt = 0; nt < 8; ++nt) {
        int f = nt * 16 + l15;
        float bv = bo[f];
        #pragma unroll
        for (int rr = 0; rr < 4; ++rr) {
            int m = m0 + q * 4 + rr;              // m = t*256 + b (16-tile never crosses t)
            int b = m & 255, t = m >> 8;
            out[(size_t)b * (T_ * F_) + (size_t)t * F_ + f] = sigf(acc[nt][rr] + bv);
        }
    }
}

// ---------------------------------------------------------------------------
extern "C" void kernel_launch(void* const* d_in, const int* in_sizes, int n_in,
                              void* d_out, int out_size, void* d_ws, size_t ws_size,
                              hipStream_t stream) {
    const float* conductor = (const float*)d_in[0];
    const float* teacher   = (const float*)d_in[1];
    const float* h0        = (const float*)d_in[2];
    const float* c0        = (const float*)d_in[3];
    const float* W         = (const float*)d_in[4];
    const float* U         = (const float*)d_in[5];
    const float* b         = (const float*)d_in[6];
    const float* Wo        = (const float*)d_in[7];
    const float* bo        = (const float*)d_in[8];

    float* out = (float*)d_out;
    float* hT  = out + (size_t)B_ * T_ * F_;        // offset 16777216
    float* cT  = hT + B_ * DU_;                     // offset 16908288 (also working c)

    // Workspace layout (needs ~645 MB)
    char* ws = (char*)d_ws;
    unsigned short* Zx  = (unsigned short*)ws;                         // 131072*2048*2 = 512 MB
    unsigned short* hs  = (unsigned short*)(ws + (size_t)536870912);   // 513*131072*2  = 128.25 MB
    unsigned short* Wt  = (unsigned short*)(ws + 536870912 + (size_t)134479872); // [2048][640]
    unsigned short* Ut  = Wt + (size_t)NG * KX;                        // [2048][512]
    unsigned short* Wot = Ut + (size_t)NG * DU_;                       // [128][512]

    // prep (runs every call: re-poisoned ws/d_out each timed launch)
    k_transpose<<<dim3(64, 20), 256, 0, stream>>>(W,  Wt,  KX,  NG);
    k_transpose<<<dim3(64, 16), 256, 0, stream>>>(U,  Ut,  DU_, NG);
    k_transpose<<<dim3(4, 16),  256, 0, stream>>>(Wo, Wot, DU_, F_);
    k_init<<<512, 256, 0, stream>>>(h0, c0, hs, cT);

    // input-side GEMM for all timesteps
    k_zx<<<dim3(16, 1024), 256, 0, stream>>>(teacher, conductor, b, Wt, Zx);

    // sequential recurrence
    for (int t = 0; t < T_; ++t)
        k_step<<<dim3(16, 16), 256, 0, stream>>>(t, Zx, hs, Ut, cT, hT);

    // batched output projection
    k_out<<<2048, 256, 0, stream>>>(hs, Wot, bo, out);
}